// Round 11
// baseline (197.090 us; speedup 1.0000x reference)
//
#include <hip/hip_runtime.h>

typedef unsigned int uint;
typedef unsigned short ushort;
typedef short bf16x8 __attribute__((ext_vector_type(8)));
typedef _Float16 f16x8 __attribute__((ext_vector_type(8)));
typedef float f32x4 __attribute__((ext_vector_type(4)));

#define NEG_SLOPE 0.2f

// ---------------- workspace layout (bytes) ----------------
#define WS_HIST 0                       // 4*4096*4 = 65536
#define WS_DBL  65536                   // 88 doubles
#define WS_BLV  (WS_DBL + 704)         // 60 floats
#define WS_WA   (WS_BLV + 256)        // 5tf x 16 x 128 bf16 = 20480 B
#define WS_W2A  (WS_WA + 20480)       // 5tf x 5step x 64lane x 8 f16 = 25600 B
#define WS_ZERO_BYTES (WS_DBL + 704)

// x LDS: 2 parity copies x 3 slots x [3ci][20y][22x] bf16 (no zero slot; OOB handled by zero A-weights)
#define XSLOT 1320
#define XCOPY 3960    // 3*1320
#define XTOT  7920
// h2 LDS: [18y][18x][20ch-stride] (40B pos stride = 10 banks -> 2-way = free; 8B aligned)
#define HCH 20
#define HROW 360      // 18*20

__device__ __forceinline__ float leakyf(float x) { return fmaxf(x, NEG_SLOPE * x); }

__device__ __forceinline__ ushort f2bf(float f) {
  uint u = __float_as_uint(f);
  uint r = u + 0x7FFFu + ((u >> 16) & 1u);
  return (ushort)(r >> 16);
}
// pack 2 f32 -> 2 f16 in one dword (v_cvt_pkrtz_f16_f32)
__device__ __forceinline__ uint cvt_pk_u32(float a, float b) {
  union { __fp16 __attribute__((ext_vector_type(2))) h; uint u; } c;
  c.h = __builtin_amdgcn_cvt_pkrtz(a, b);
  return c.u;
}

// ---------------- fused stats: i-plane sums + center G/B stats + median hist + j sums ----------------
__global__ __launch_bounds__(256) void stats_kernel(const float* __restrict__ gi,
                                                    const float* __restrict__ gj,
                                                    double* __restrict__ sums,
                                                    uint* __restrict__ hist) {
  __shared__ double red[256];
  __shared__ uint lh[4096];
  const int plane = blockIdx.y;          // 0..59 = i planes, 60..71 = j planes
  const int chunk = blockIdx.x;          // 0..31
  const int tid = threadIdx.x;

  if (plane >= 60) {
    const int jp = plane - 60;
    const float4* base = (const float4*)(gj + (size_t)jp * 262144);
    double dsum = 0.0;
    for (int k = 0; k < 8; ++k) {
      float4 v = base[chunk * 2048 + k * 256 + tid];
      dsum += (double)v.x + (double)v.y + (double)v.z + (double)v.w;
    }
    red[tid] = dsum; __syncthreads();
    for (int off = 128; off > 0; off >>= 1) { if (tid < off) red[tid] += red[tid + off]; __syncthreads(); }
    if (tid == 0) atomicAdd(&sums[60 + jp], red[0]);
    return;
  }

  const int b = plane / 15;
  const int rem = plane % 15;
  const int c = rem / 5;
  const int t = rem % 5;
  const float4* base = (const float4*)(gi + (size_t)plane * 262144);
  const bool dostat = (c >= 1 && t == 2);
  const bool domed = (c == 0 && t == 2);
  if (domed) {
    for (int i = tid; i < 4096; i += 256) lh[i] = 0;
    __syncthreads();
  }
  double dsum = 0.0, dsx = 0.0, dsx2 = 0.0;
  for (int k = 0; k < 8; ++k) {
    float4 v = base[chunk * 2048 + k * 256 + tid];
    dsum += (double)v.x + (double)v.y + (double)v.z + (double)v.w;
    if (dostat || domed) {
      float arr[4] = {v.x, v.y, v.z, v.w};
#pragma unroll
      for (int q = 0; q < 4; ++q) {
        float x = fminf(fmaxf(arr[q], 0.f), 1.f) * 255.f;
        if (domed) {
          int bin = (int)(x * (4096.0f / 255.0f));
          if (bin > 4095) bin = 4095;
          atomicAdd(&lh[bin], 1u);
        } else {
          dsx += (double)x;
          dsx2 += (double)x * (double)x;
        }
      }
    }
  }
  red[tid] = dsum; __syncthreads();
  for (int off = 128; off > 0; off >>= 1) { if (tid < off) red[tid] += red[tid + off]; __syncthreads(); }
  if (tid == 0) atomicAdd(&sums[plane], red[0]);
  __syncthreads();
  if (dostat) {
    red[tid] = dsx; __syncthreads();
    for (int off = 128; off > 0; off >>= 1) { if (tid < off) red[tid] += red[tid + off]; __syncthreads(); }
    if (tid == 0) atomicAdd(&sums[72 + b * 2 + (c - 1)], red[0]);
    __syncthreads();
    red[tid] = dsx2; __syncthreads();
    for (int off = 128; off > 0; off >>= 1) { if (tid < off) red[tid] += red[tid + off]; __syncthreads(); }
    if (tid == 0) atomicAdd(&sums[80 + b * 2 + (c - 1)], red[0]);
  }
  if (domed) {
    for (int i = tid; i < 4096; i += 256) { uint v = lh[i]; if (v) atomicAdd(&hist[b * 4096 + i], v); }
  }
}

// ---------------- weight prep: per-tf bf16 conv1 A tables (5x16x128) + f16 conv2 A-table ----------------
// wA5[tf][o][k]: g=k>>2, kw=k&3; zero when g>=27 || kw==3 || (tf+kd-1) outside [0,4].
__global__ void setup_kernel(const float* __restrict__ w_t1, const float* __restrict__ w_t2,
                             ushort* __restrict__ wA5, ushort* __restrict__ w2A) {
  const int tid = threadIdx.x;
  for (int idx = tid; idx < 10240; idx += 256) {
    int tf = idx >> 11;
    int r = idx & 2047;
    int o = r >> 7, k = r & 127, g = k >> 2, kw = k & 3;
    float v = 0.f;
    if (g < 27 && kw < 3) {
      int ci = g / 9, kd = (g % 9) / 3, kh = g % 3;
      int f = tf + kd - 1;
      if (f >= 0 && f <= 4)
        v = w_t1[o * 81 + ci * 27 + kd * 9 + kh * 3 + kw];
    }
    wA5[idx] = f2bf(v);
  }
  for (int idx = tid; idx < 12800; idx += 256) {
    int j = idx & 7;
    int lane = (idx >> 3) & 63;
    int rest = idx >> 9;            // 0..24
    int step = rest % 5;
    int tf = rest / 5;
    int ln = lane & 15, kb = lane >> 4;
    int k = kb * 8 + j;
    int tap = step * 2 + (k >> 4);
    int ch = k & 15;
    float v = 0.f;
    if (ln < 5 && tap < 9) {
      int kd = tf + 1 - ln;
      if (kd >= 0 && kd <= 2) v = w_t2[ch * 27 + kd * 9 + tap];
    }
    union { ushort s; _Float16 h; } cv; cv.h = (_Float16)v;
    w2A[idx] = cv.s;
  }
}

// ---------------- finalize: median scan + stats -> MLP -> blv ----------------
__global__ __launch_bounds__(256) void finalize_kernel(const uint* __restrict__ hist,
                                const double* __restrict__ sums,
                                const float* __restrict__ w_bl1, const float* __restrict__ b_bl1,
                                const float* __restrict__ w_bl2, const float* __restrict__ b_bl2,
                                const float* __restrict__ w1, float* __restrict__ blv) {
  __shared__ uint s[256];
  __shared__ float fv[2];
  __shared__ float rmed_s[4];
  const int tid = threadIdx.x;
  for (int b = 0; b < 4; ++b) {
    const uint* h = hist + b * 4096;
    uint loc[16]; uint part = 0;
#pragma unroll
    for (int q = 0; q < 16; ++q) { loc[q] = h[tid * 16 + q]; part += loc[q]; }
    s[tid] = part; __syncthreads();
    for (int off = 1; off < 256; off <<= 1) {
      uint v = (tid >= off) ? s[tid - off] : 0u;
      __syncthreads(); s[tid] += v; __syncthreads();
    }
    uint pref = s[tid] - part;
#pragma unroll
    for (int m = 0; m < 2; ++m) {
      uint k = 131071u + (uint)m;
      if (k >= pref && k < pref + part) {
        uint cum = pref;
        for (int q = 0; q < 16; ++q) {
          if (k < cum + loc[q]) { fv[m] = ((float)(tid * 16 + q) + 0.5f) * (255.f / 4096.f); break; }
          cum += loc[q];
        }
      }
    }
    __syncthreads();
    if (tid == 0) rmed_s[b] = 0.5f * (fv[0] + fv[1]);
    __syncthreads();
  }
  if (tid < 20) {
    const int b = tid / 5, t = tid % 5;
    const double inv = 1.0 / 262144.0;
    float bl2[3];
    bl2[0] = 140.f / (1.f + 14.4f * expf(-0.034f * rmed_s[b]));
    for (int c = 1; c < 3; ++c) {
      double m = sums[72 + b * 2 + (c - 1)] * inv;
      double ex2 = sums[80 + b * 2 + (c - 1)] * inv;
      double var = ex2 - m * m;
      if (var < 0.0) var = 0.0;
      bl2[c] = (float)(1.13 * m + 1.11 * sqrt(var) - 25.6);
    }
#pragma unroll
    for (int c = 0; c < 3; ++c)
      bl2[c] = fminf(fmaxf(bl2[c], 5.f), 250.f) * (1.f / 255.f);
    float diff[3];
    for (int c = 0; c < 3; ++c)
      diff[c] = (float)((sums[(b * 3 + c) * 5 + t] - sums[60 + b * 3 + c]) * inv);
    float h1[16];
    for (int o = 0; o < 16; ++o) {
      float sv = b_bl1[o];
      for (int c = 0; c < 3; ++c) sv += w_bl1[o * 3 + c] * diff[c];
      h1[o] = leakyf(sv);
    }
    const float w1v = w1[0];
    for (int c = 0; c < 3; ++c) {
      float sv = b_bl2[c];
      for (int o = 0; o < 16; ++o) sv += w_bl2[c * 16 + o] * h1[o];
      float sg = 1.f / (1.f + expf(-sv));
      blv[(b * 3 + c) * 5 + t] = bl2[c] + w1v * sg;
    }
  }
}

// ---------------- fused: x -> conv1 (MFMA bf16) -> leaky -> conv2 (MFMA f16) -> sigmoid ----------------
// R10 structure; LDS diet: no zero x-slot (per-tf zeroed A tables instead), h2 stride 20.
// ~28.9 KB LDS -> 5 blocks/CU.
__global__ __launch_bounds__(256) void fused_kernel(
    const float* __restrict__ gi, const float* __restrict__ gj,
    const ushort* __restrict__ wA5, const float* __restrict__ b_t1,
    const ushort* __restrict__ w2Ag, const float* __restrict__ b_t2,
    const float* __restrict__ w2p, const float* __restrict__ t_bias,
    const float* __restrict__ blv, float* __restrict__ out) {
  __shared__ __align__(16) ushort xsh[XTOT];       // 2 parity copies x 3 slots x [3][20][22] bf16
  __shared__ __align__(16) ushort h2sh[324 * HCH]; // h2 f16 [18y][18x][20ch-stride]
  __shared__ float blv_s[15];

  const int b = blockIdx.z;
  // XCD-aware swizzle: lin%8 = XCD; each XCD gets a contiguous 4-row tile band (L2-resident halos)
  const int lin = blockIdx.y * 32 + blockIdx.x;
  const int swz = (lin & 7) * 128 + (lin >> 3);
  const int tY = swz >> 5, tX = swz & 31;
  const int tid = threadIdx.x;
  const int wv = tid >> 6;
  const int lane = tid & 63;
  const int ln = lane & 15;
  const int kb = lane >> 4;
  const int ty = tid >> 4, tx = tid & 15;
  const int gy = tY * 16 + ty, gx = tX * 16 + tx;
  const int ybase = tY * 16 - 2, xbase = tX * 16 - 2;

  if (tid < 15) blv_s[tid] = blv[b * 15 + tid];
  for (int i = tid; i < XTOT / 2; i += 256) ((uint*)xsh)[i] = 0u;   // finite everywhere (0*stale-safe)

  f32x4 bias4;
#pragma unroll
  for (int r = 0; r < 4; ++r) bias4[r] = b_t1[kb * 4 + r];

  // conv1 per-lane k-group descriptors
  int sbase[8], kdE[8];
#pragma unroll
  for (int e = 0; e < 8; ++e) {
    int m = e >> 1, j = e & 1;
    int g = m * 8 + kb * 2 + j;
    int ci = 0, kd = 0, kh = 0;
    if (g < 27) { ci = g / 9; kd = (g % 9) / 3; kh = g % 3; } else { kd = 99; }
    sbase[e] = ci * 440 + kh * 22;
    kdE[e] = kd;
  }

  // conv1 per-tile statics (tile = wv + i*4)
  int qT[6], hOffT[6];
  uint tmask = 0;   // bit i: pos<324 (store valid); bit i+8: inimg
#pragma unroll
  for (int i = 0; i < 6; ++i) {
    int tile = wv + i * 4;
    int pos = tile * 16 + ln;
    int pe = pos < 324 ? pos : 323;
    int y0 = pe / 18, x0 = pe - y0 * 18;
    int p = x0 & 1;
    qT[i] = y0 * 22 + x0 - p + p * XCOPY;
    hOffT[i] = (y0 * 18 + x0) * HCH + kb * 4;
    int gyh = tY * 16 - 1 + y0, gxh = tX * 16 - 1 + x0;
    if (pos < 324) tmask |= 1u << i;
    if (gyh >= 0 && gyh < 512 && gxh >= 0 && gxh < 512) tmask |= 1u << (i + 8);
  }

  // conv2 per-lane B offsets (elem units)
  int bOff[5];
#pragma unroll
  for (int s = 0; s < 5; ++s) {
    int tap = s * 2 + (kb >> 1); if (tap > 8) tap = 8;
    int kh = tap / 3, kw = tap - kh * 3;
    bOff[s] = kh * HROW + kw * HCH + (kb & 1) * 8 + ln * HCH;
  }

  // staging precompute (k = 0..4, idx = tid + k*256 over [3][20][20])
  int qi5[5], eb5[5], civ5[5];
  float jv5[5];
  uint vmask = 0;
#pragma unroll
  for (int k = 0; k < 5; ++k) {
    int idx = tid + k * 256;
    int idc = idx < 1200 ? idx : 0;
    int ci = idc / 400, rem = idc - ci * 400;
    int ys = rem / 20, xx = rem - ys * 20;
    int gyy = ybase + ys, gxx = xbase + xx;
    bool inb = (idx < 1200) && gyy >= 0 && gyy < 512 && gxx >= 0 && gxx < 512;
    int cy = gyy < 0 ? 0 : (gyy > 511 ? 511 : gyy);
    int cx = gxx < 0 ? 0 : (gxx > 511 ? 511 : gxx);
    int spc = cy * 512 + cx;
    qi5[k] = (b * 3 + ci) * 1310720 + spc;
    jv5[k] = gj[(b * 3 + ci) * 262144 + spc];
    eb5[k] = ci * 440 + ys * 22 + xx;
    civ5[k] = ci * 5;
    if (inb) vmask |= 1u << k;
    if (xx > 0) vmask |= 1u << (k + 8);
  }

  const float w2v = w2p[0];

  auto issue_loads = [&](int f, float* ivr) {
    const int fo = f * 262144;
    ivr[0] = gi[qi5[0] + fo];
    ivr[1] = gi[qi5[1] + fo];
    ivr[2] = gi[qi5[2] + fo];
    ivr[3] = gi[qi5[3] + fo];
    ivr[4] = (tid < 176) ? gi[qi5[4] + fo] : 0.f;
  };
  auto stage_frame = [&](int f, const float* ivr) {
    const int slot = f % 3;
    const int sb2 = slot * XSLOT;
#pragma unroll
    for (int k = 0; k < 5; ++k) {
      if (k == 4 && tid >= 176) break;
      float iv = ivr[k];
      float bv = blv_s[civ5[k] + f];
      float num = iv - bv;
      float den = jv5[k] - bv + 1e-8f;
      float xv = ((vmask >> k) & 1u) ? fmaf(w2v, num * __builtin_amdgcn_rcpf(den), iv) : 0.f;
      ushort hx = f2bf(xv);
      int ebb = sb2 + eb5[k];
      xsh[ebb] = hx;
      if ((vmask >> (k + 8)) & 1u) xsh[ebb + XCOPY - 1] = hx;   // copy1[eb-1] = x[eb]
    }
  };

  // ---- prologue: issue loads for frames 0,1; barrier; bl writes; stage 0,1 ----
  float ivr0[5], ivr1[5];
  issue_loads(0, ivr0);
  issue_loads(1, ivr1);

  __syncthreads();   // zero-init + blv_s visible to ALL waves

#pragma unroll
  for (int c = 0; c < 3; ++c)
#pragma unroll
    for (int t = 0; t < 5; ++t)
      out[(((b * 3 + c) * 5 + t) * 512 + gy) * 512 + gx] = blv_s[c * 5 + t];

  stage_frame(0, ivr0);
  stage_frame(1, ivr1);
  __syncthreads();

  f32x4 acc2[4];
#pragma unroll
  for (int u = 0; u < 4; ++u) acc2[u] = (f32x4){0.f, 0.f, 0.f, 0.f};

#pragma unroll
  for (int tf = 0; tf < 5; ++tf) {
    // prefetch gi for frame tf+2 BEFORE conv1: conv1 phase covers the latency
    float ivr[5];
    if (tf < 3) issue_loads(tf + 2, ivr);

    // per-tf conv1 A fragments (zero-weighted for OOB kd) + conv2 A fragments
    union { uint4 u; bf16x8 v; } a4[4];
#pragma unroll
    for (int m = 0; m < 4; ++m)
      a4[m].u = *(const uint4*)(wA5 + tf * 2048 + ln * 128 + m * 32 + kb * 8);
    union { uint4 u; f16x8 v; } aw[5];
#pragma unroll
    for (int s = 0; s < 5; ++s)
      aw[s].u = *(const uint4*)(w2Ag + ((tf * 5 + s) * 64 + lane) * 8);

    // per-tf conv1 slot bases: OOB/pad -> slot 0 (finite data, zero A-weight)
    int baseE[8];
#pragma unroll
    for (int e = 0; e < 8; ++e) {
      int f = tf + kdE[e] - 1;
      int sl = (f < 0 || f > 4 || kdE[e] == 99) ? 0 : (f % 3);
      baseE[e] = sbase[e] + sl * XSLOT;
    }

    // ---- conv1 via MFMA ----
#pragma unroll
    for (int i = 0; i < 6; ++i) {
      if (i == 5 && wv != 0) continue;   // only wave 0 owns tile 20
      const int q = qT[i];
      uint u0[8], u1[8];
#pragma unroll
      for (int e = 0; e < 8; ++e) {
        const uint* pu = (const uint*)(xsh + (baseE[e] + q));
        u0[e] = pu[0]; u1[e] = pu[1];
      }
      f32x4 acc = bias4;
#pragma unroll
      for (int m = 0; m < 4; ++m) {
        union { uint4 u; bf16x8 v; } bfr;
        bfr.u = make_uint4(u0[2 * m], u1[2 * m], u0[2 * m + 1], u1[2 * m + 1]);
        acc = __builtin_amdgcn_mfma_f32_16x16x32_bf16(a4[m].v, bfr.v, acc, 0, 0, 0);
      }
      const bool inimg = (tmask >> (i + 8)) & 1u;
      float r0 = inimg ? leakyf(acc[0]) : 0.f;
      float r1 = inimg ? leakyf(acc[1]) : 0.f;
      float r2 = inimg ? leakyf(acc[2]) : 0.f;
      float r3 = inimg ? leakyf(acc[3]) : 0.f;
      uint p0 = cvt_pk_u32(r0, r1);
      uint p1 = cvt_pk_u32(r2, r3);
      if ((tmask >> i) & 1u)
        *(uint2*)(h2sh + hOffT[i]) = make_uint2(p0, p1);
    }
    __syncthreads();

    // ---- conv2(tf) MFMA, then x-write(tf+2) from prefetched regs ----
#pragma unroll
    for (int u = 0; u < 4; ++u) {
      const int tt = wv + u * 4;
      const ushort* hb = h2sh + tt * HROW;
#pragma unroll
      for (int s = 0; s < 5; ++s) {
        uint2 lo = *(const uint2*)(hb + bOff[s]);
        uint2 hi = *(const uint2*)(hb + bOff[s] + 4);
        union { uint4 u4; f16x8 v; } bfr;
        bfr.u4 = make_uint4(lo.x, lo.y, hi.x, hi.y);
        acc2[u] = __builtin_amdgcn_mfma_f32_16x16x32_f16(aw[s].v, bfr.v, acc2[u], 0, 0, 0);
      }
    }

    if (tf < 3) stage_frame(tf + 2, ivr);
    __syncthreads();
  }

  // ---- redistribute D[t][pos] through LDS (reuse xsh) and store t-output ----
  float* sredf = (float*)xsh;
#pragma unroll
  for (int u = 0; u < 4; ++u) {
    const int tt = wv + u * 4;
    if (kb == 0) {
#pragma unroll
      for (int r = 0; r < 4; ++r)
        sredf[r * 256 + tt * 16 + ln] = acc2[u][r];      // rows 0..3 = t 0..3
    } else if (kb == 1) {
      sredf[4 * 256 + tt * 16 + ln] = acc2[u][0];        // row 4 = t 4
    }
  }
  __syncthreads();

  const float bt2 = b_t2[0];
#pragma unroll
  for (int t = 0; t < 5; ++t) {
    float tv = 1.f / (1.f + __expf(-(sredf[t * 256 + tid] + bt2))) + t_bias[t];
    out[15728640 + ((b * 5 + t) * 512 + gy) * 512 + gx] = tv;
  }
}

extern "C" void kernel_launch(void* const* d_in, const int* in_sizes, int n_in,
                              void* d_out, int out_size, void* d_ws, size_t ws_size,
                              hipStream_t stream) {
  const float* gi = (const float*)d_in[0];
  const float* gj = (const float*)d_in[1];
  const float* w_bl1 = (const float*)d_in[2];
  const float* b_bl1 = (const float*)d_in[3];
  const float* w_bl2 = (const float*)d_in[4];
  const float* b_bl2 = (const float*)d_in[5];
  const float* w_t1 = (const float*)d_in[6];
  const float* b_t1 = (const float*)d_in[7];
  const float* w_t2 = (const float*)d_in[8];
  const float* b_t2 = (const float*)d_in[9];
  const float* w1 = (const float*)d_in[10];
  const float* w2 = (const float*)d_in[11];
  const float* t_bias = (const float*)d_in[12];
  float* out = (float*)d_out;
  char* ws = (char*)d_ws;

  uint* hist = (uint*)(ws + WS_HIST);
  double* sums = (double*)(ws + WS_DBL);
  float* blv = (float*)(ws + WS_BLV);
  ushort* wA5 = (ushort*)(ws + WS_WA);
  ushort* w2A = (ushort*)(ws + WS_W2A);

  hipMemsetAsync(ws, 0, WS_ZERO_BYTES, stream);

  setup_kernel<<<1, 256, 0, stream>>>(w_t1, w_t2, wA5, w2A);
  stats_kernel<<<dim3(32, 72), 256, 0, stream>>>(gi, gj, sums, hist);
  finalize_kernel<<<1, 256, 0, stream>>>(hist, sums, w_bl1, b_bl1, w_bl2, b_bl2, w1, blv);
  fused_kernel<<<dim3(32, 32, 4), 256, 0, stream>>>(gi, gj, wA5, b_t1, w2A, b_t2, w2, t_bias, blv, out);
}

// Round 12
// 171.343 us; speedup vs baseline: 1.1503x; 1.1503x over previous
//
#include <hip/hip_runtime.h>

typedef unsigned int uint;
typedef unsigned short ushort;
typedef short bf16x8 __attribute__((ext_vector_type(8)));
typedef _Float16 f16x8 __attribute__((ext_vector_type(8)));
typedef float f32x4 __attribute__((ext_vector_type(4)));

#define NEG_SLOPE 0.2f

// ---------------- workspace layout (bytes) ----------------
#define WS_HIST 0                       // 4*4096*4 = 65536
#define WS_DBL  65536                   // 88 doubles
#define WS_BLV  (WS_DBL + 704)         // 60 floats
#define WS_WA   (WS_BLV + 256)        // 16x128 bf16 = 4096 B
#define WS_W2A  (WS_WA + 4096)        // 5tf x 5step x 64lane x 8 f16 = 25600 B
#define WS_ZERO_BYTES (WS_DBL + 704)

// h2 LDS geometry: [18 rows][18 cols][28 ch-stride] (56B position stride = 14 banks,
// ln*7 mod 32 is a permutation -> conflict-free conv2 reads / conv1 writes)
#define HCH 28
#define HROW 504      // 18*28

__device__ __forceinline__ float leakyf(float x) { return fmaxf(x, NEG_SLOPE * x); }

__device__ __forceinline__ ushort f2bf(float f) {
  uint u = __float_as_uint(f);
  uint r = u + 0x7FFFu + ((u >> 16) & 1u);
  return (ushort)(r >> 16);
}
// pack 2 f32 -> 2 f16 in one dword (v_cvt_pkrtz_f16_f32)
__device__ __forceinline__ uint cvt_pk_u32(float a, float b) {
  union { __fp16 __attribute__((ext_vector_type(2))) h; uint u; } c;
  c.h = __builtin_amdgcn_cvt_pkrtz(a, b);
  return c.u;
}

// ---------------- fused stats: i-plane sums + center G/B stats + median hist + j sums ----------------
__global__ __launch_bounds__(256) void stats_kernel(const float* __restrict__ gi,
                                                    const float* __restrict__ gj,
                                                    double* __restrict__ sums,
                                                    uint* __restrict__ hist) {
  __shared__ double red[256];
  __shared__ uint lh[4096];
  const int plane = blockIdx.y;          // 0..59 = i planes, 60..71 = j planes
  const int chunk = blockIdx.x;          // 0..31
  const int tid = threadIdx.x;

  if (plane >= 60) {
    const int jp = plane - 60;
    const float4* base = (const float4*)(gj + (size_t)jp * 262144);
    double dsum = 0.0;
    for (int k = 0; k < 8; ++k) {
      float4 v = base[chunk * 2048 + k * 256 + tid];
      dsum += (double)v.x + (double)v.y + (double)v.z + (double)v.w;
    }
    red[tid] = dsum; __syncthreads();
    for (int off = 128; off > 0; off >>= 1) { if (tid < off) red[tid] += red[tid + off]; __syncthreads(); }
    if (tid == 0) atomicAdd(&sums[60 + jp], red[0]);
    return;
  }

  const int b = plane / 15;
  const int rem = plane % 15;
  const int c = rem / 5;
  const int t = rem % 5;
  const float4* base = (const float4*)(gi + (size_t)plane * 262144);
  const bool dostat = (c >= 1 && t == 2);
  const bool domed = (c == 0 && t == 2);
  if (domed) {
    for (int i = tid; i < 4096; i += 256) lh[i] = 0;
    __syncthreads();
  }
  double dsum = 0.0, dsx = 0.0, dsx2 = 0.0;
  for (int k = 0; k < 8; ++k) {
    float4 v = base[chunk * 2048 + k * 256 + tid];
    dsum += (double)v.x + (double)v.y + (double)v.z + (double)v.w;
    if (dostat || domed) {
      float arr[4] = {v.x, v.y, v.z, v.w};
#pragma unroll
      for (int q = 0; q < 4; ++q) {
        float x = fminf(fmaxf(arr[q], 0.f), 1.f) * 255.f;
        if (domed) {
          int bin = (int)(x * (4096.0f / 255.0f));
          if (bin > 4095) bin = 4095;
          atomicAdd(&lh[bin], 1u);
        } else {
          dsx += (double)x;
          dsx2 += (double)x * (double)x;
        }
      }
    }
  }
  red[tid] = dsum; __syncthreads();
  for (int off = 128; off > 0; off >>= 1) { if (tid < off) red[tid] += red[tid + off]; __syncthreads(); }
  if (tid == 0) atomicAdd(&sums[plane], red[0]);
  __syncthreads();
  if (dostat) {
    red[tid] = dsx; __syncthreads();
    for (int off = 128; off > 0; off >>= 1) { if (tid < off) red[tid] += red[tid + off]; __syncthreads(); }
    if (tid == 0) atomicAdd(&sums[72 + b * 2 + (c - 1)], red[0]);
    __syncthreads();
    red[tid] = dsx2; __syncthreads();
    for (int off = 128; off > 0; off >>= 1) { if (tid < off) red[tid] += red[tid + off]; __syncthreads(); }
    if (tid == 0) atomicAdd(&sums[80 + b * 2 + (c - 1)], red[0]);
  }
  if (domed) {
    for (int i = tid; i < 4096; i += 256) { uint v = lh[i]; if (v) atomicAdd(&hist[b * 4096 + i], v); }
  }
}

// ---------------- weight prep: bf16 conv1 A (16x128) + f16 conv2 A-table ----------------
__global__ void setup_kernel(const float* __restrict__ w_t1, const float* __restrict__ w_t2,
                             ushort* __restrict__ wA, ushort* __restrict__ w2A) {
  const int tid = threadIdx.x;
  for (int idx = tid; idx < 2048; idx += 256) {
    int o = idx >> 7, k = idx & 127, g = k >> 2, kw = k & 3;
    float v = 0.f;
    if (g < 27 && kw < 3) {
      int ci = g / 9, kd = (g % 9) / 3, kh = g % 3;
      v = w_t1[o * 81 + ci * 27 + kd * 9 + kh * 3 + kw];
    }
    wA[idx] = f2bf(v);
  }
  for (int idx = tid; idx < 12800; idx += 256) {
    int j = idx & 7;
    int lane = (idx >> 3) & 63;
    int rest = idx >> 9;            // 0..24
    int step = rest % 5;
    int tf = rest / 5;
    int ln = lane & 15, kb = lane >> 4;
    int k = kb * 8 + j;
    int tap = step * 2 + (k >> 4);
    int ch = k & 15;
    float v = 0.f;
    if (ln < 5 && tap < 9) {
      int kd = tf + 1 - ln;
      if (kd >= 0 && kd <= 2) v = w_t2[ch * 27 + kd * 9 + tap];
    }
    union { ushort s; _Float16 h; } cv; cv.h = (_Float16)v;
    w2A[idx] = cv.s;
  }
}

// ---------------- finalize: median scan + stats -> MLP -> blv ----------------
__global__ __launch_bounds__(256) void finalize_kernel(const uint* __restrict__ hist,
                                const double* __restrict__ sums,
                                const float* __restrict__ w_bl1, const float* __restrict__ b_bl1,
                                const float* __restrict__ w_bl2, const float* __restrict__ b_bl2,
                                const float* __restrict__ w1, float* __restrict__ blv) {
  __shared__ uint s[256];
  __shared__ float fv[2];
  __shared__ float rmed_s[4];
  const int tid = threadIdx.x;
  for (int b = 0; b < 4; ++b) {
    const uint* h = hist + b * 4096;
    uint loc[16]; uint part = 0;
#pragma unroll
    for (int q = 0; q < 16; ++q) { loc[q] = h[tid * 16 + q]; part += loc[q]; }
    s[tid] = part; __syncthreads();
    for (int off = 1; off < 256; off <<= 1) {
      uint v = (tid >= off) ? s[tid - off] : 0u;
      __syncthreads(); s[tid] += v; __syncthreads();
    }
    uint pref = s[tid] - part;
#pragma unroll
    for (int m = 0; m < 2; ++m) {
      uint k = 131071u + (uint)m;
      if (k >= pref && k < pref + part) {
        uint cum = pref;
        for (int q = 0; q < 16; ++q) {
          if (k < cum + loc[q]) { fv[m] = ((float)(tid * 16 + q) + 0.5f) * (255.f / 4096.f); break; }
          cum += loc[q];
        }
      }
    }
    __syncthreads();
    if (tid == 0) rmed_s[b] = 0.5f * (fv[0] + fv[1]);
    __syncthreads();
  }
  if (tid < 20) {
    const int b = tid / 5, t = tid % 5;
    const double inv = 1.0 / 262144.0;
    float bl2[3];
    bl2[0] = 140.f / (1.f + 14.4f * expf(-0.034f * rmed_s[b]));
    for (int c = 1; c < 3; ++c) {
      double m = sums[72 + b * 2 + (c - 1)] * inv;
      double ex2 = sums[80 + b * 2 + (c - 1)] * inv;
      double var = ex2 - m * m;
      if (var < 0.0) var = 0.0;
      bl2[c] = (float)(1.13 * m + 1.11 * sqrt(var) - 25.6);
    }
#pragma unroll
    for (int c = 0; c < 3; ++c)
      bl2[c] = fminf(fmaxf(bl2[c], 5.f), 250.f) * (1.f / 255.f);
    float diff[3];
    for (int c = 0; c < 3; ++c)
      diff[c] = (float)((sums[(b * 3 + c) * 5 + t] - sums[60 + b * 3 + c]) * inv);
    float h1[16];
    for (int o = 0; o < 16; ++o) {
      float sv = b_bl1[o];
      for (int c = 0; c < 3; ++c) sv += w_bl1[o * 3 + c] * diff[c];
      h1[o] = leakyf(sv);
    }
    const float w1v = w1[0];
    for (int c = 0; c < 3; ++c) {
      float sv = b_bl2[c];
      for (int o = 0; o < 16; ++o) sv += w_bl2[c * 16 + o] * h1[o];
      float sg = 1.f / (1.f + expf(-sv));
      blv[(b * 3 + c) * 5 + t] = bl2[c] + w1v * sg;
    }
  }
}

// ---------------- fused: x -> conv1 (MFMA bf16) -> leaky -> conv2 (MFMA f16) -> sigmoid ----------------
// R10 structure verbatim; single delta: __launch_bounds__(256,3) -> reg cap ~170 to test the
// hypothesis that hidden AGPR allocation puts the wave in the 129-256 bucket (2 waves/SIMD).
__global__ __launch_bounds__(256, 3) void fused_kernel(
    const float* __restrict__ gi, const float* __restrict__ gj,
    const ushort* __restrict__ wAg, const float* __restrict__ b_t1,
    const ushort* __restrict__ w2Ag, const float* __restrict__ b_t2,
    const float* __restrict__ w2p, const float* __restrict__ t_bias,
    const float* __restrict__ blv, float* __restrict__ out) {
  __shared__ __align__(16) ushort xsh[10560];     // 2 parity copies x 4 slots x [3][20][22] bf16
  __shared__ __align__(16) ushort h2sh[324 * HCH]; // h2 f16 [18y][18x][28ch-stride]
  __shared__ float blv_s[15];

  const int b = blockIdx.z;
  // XCD-aware swizzle: lin%8 = XCD; each XCD gets a contiguous 4-row tile band (L2-resident halos)
  const int lin = blockIdx.y * 32 + blockIdx.x;
  const int swz = (lin & 7) * 128 + (lin >> 3);
  const int tY = swz >> 5, tX = swz & 31;
  const int tid = threadIdx.x;
  const int wv = tid >> 6;
  const int lane = tid & 63;
  const int ln = lane & 15;
  const int kb = lane >> 4;
  const int ty = tid >> 4, tx = tid & 15;
  const int gy = tY * 16 + ty, gx = tX * 16 + tx;
  const int ybase = tY * 16 - 2, xbase = tX * 16 - 2;

  if (tid < 15) blv_s[tid] = blv[b * 15 + tid];
  for (int i = tid; i < 5280; i += 256) ((uint*)xsh)[i] = 0u;

  // conv1 A fragments + bias
  union { uint4 u; bf16x8 v; } a4[4];
#pragma unroll
  for (int m = 0; m < 4; ++m)
    a4[m].u = *(const uint4*)(wAg + ln * 128 + m * 32 + kb * 8);
  f32x4 bias4;
#pragma unroll
  for (int r = 0; r < 4; ++r) bias4[r] = b_t1[kb * 4 + r];

  // conv1 per-lane k-group descriptors
  int sbase[8], kdE[8];
#pragma unroll
  for (int e = 0; e < 8; ++e) {
    int m = e >> 1, j = e & 1;
    int g = m * 8 + kb * 2 + j;
    int ci = 0, kd = 0, kh = 0;
    if (g < 27) { ci = g / 9; kd = (g % 9) / 3; kh = g % 3; } else { kd = 99; }
    sbase[e] = ci * 440 + kh * 22;
    kdE[e] = kd;
  }

  // conv1 per-tile statics (tile = wv + i*4)
  int qT[6], hOffT[6];
  uint tmask = 0;   // bit i: pos<324 (store valid); bit i+8: inimg
#pragma unroll
  for (int i = 0; i < 6; ++i) {
    int tile = wv + i * 4;
    int pos = tile * 16 + ln;
    int pe = pos < 324 ? pos : 323;
    int y0 = pe / 18, x0 = pe - y0 * 18;
    int p = x0 & 1;
    qT[i] = y0 * 22 + x0 - p + p * 5280;
    hOffT[i] = (y0 * 18 + x0) * HCH + kb * 4;
    int gyh = tY * 16 - 1 + y0, gxh = tX * 16 - 1 + x0;
    if (pos < 324) tmask |= 1u << i;
    if (gyh >= 0 && gyh < 512 && gxh >= 0 && gxh < 512) tmask |= 1u << (i + 8);
  }

  // conv2 per-lane B offsets (elem units)
  int bOff[5];
#pragma unroll
  for (int s = 0; s < 5; ++s) {
    int tap = s * 2 + (kb >> 1); if (tap > 8) tap = 8;
    int kh = tap / 3, kw = tap - kh * 3;
    bOff[s] = kh * HROW + kw * HCH + (kb & 1) * 8 + ln * HCH;
  }

  // staging precompute (k = 0..4, idx = tid + k*256 over [3][20][20])
  int qi5[5], eb5[5], civ5[5];
  float jv5[5];
  uint vmask = 0;
#pragma unroll
  for (int k = 0; k < 5; ++k) {
    int idx = tid + k * 256;
    int idc = idx < 1200 ? idx : 0;
    int ci = idc / 400, rem = idc - ci * 400;
    int ys = rem / 20, xx = rem - ys * 20;
    int gyy = ybase + ys, gxx = xbase + xx;
    bool inb = (idx < 1200) && gyy >= 0 && gyy < 512 && gxx >= 0 && gxx < 512;
    int cy = gyy < 0 ? 0 : (gyy > 511 ? 511 : gyy);
    int cx = gxx < 0 ? 0 : (gxx > 511 ? 511 : gxx);
    int spc = cy * 512 + cx;
    qi5[k] = (b * 3 + ci) * 1310720 + spc;
    jv5[k] = gj[(b * 3 + ci) * 262144 + spc];
    eb5[k] = ci * 440 + ys * 22 + xx;
    civ5[k] = ci * 5;
    if (inb) vmask |= 1u << k;
    if (xx > 0) vmask |= 1u << (k + 8);
  }

  const float w2v = w2p[0];

  auto issue_loads = [&](int f, float* ivr) {
    const int fo = f * 262144;
    ivr[0] = gi[qi5[0] + fo];
    ivr[1] = gi[qi5[1] + fo];
    ivr[2] = gi[qi5[2] + fo];
    ivr[3] = gi[qi5[3] + fo];
    ivr[4] = (tid < 176) ? gi[qi5[4] + fo] : 0.f;
  };
  auto stage_frame = [&](int f, const float* ivr) {
    const int slot = f % 3;
    const int sb2 = slot * 1320;
#pragma unroll
    for (int k = 0; k < 5; ++k) {
      if (k == 4 && tid >= 176) break;
      float iv = ivr[k];
      float bv = blv_s[civ5[k] + f];
      float num = iv - bv;
      float den = jv5[k] - bv + 1e-8f;
      float xv = ((vmask >> k) & 1u) ? fmaf(w2v, num * __builtin_amdgcn_rcpf(den), iv) : 0.f;
      ushort hx = f2bf(xv);
      int ebb = sb2 + eb5[k];
      xsh[ebb] = hx;
      if ((vmask >> (k + 8)) & 1u) xsh[ebb + 5279] = hx;
    }
  };

  // ---- prologue: issue loads for frames 0,1; barrier; bl writes (blv_s now safe); stage 0,1 ----
  float ivr0[5], ivr1[5];
  issue_loads(0, ivr0);
  issue_loads(1, ivr1);

  __syncthreads();   // zero-init + blv_s visible to ALL waves

#pragma unroll
  for (int c = 0; c < 3; ++c)
#pragma unroll
    for (int t = 0; t < 5; ++t)
      out[(((b * 3 + c) * 5 + t) * 512 + gy) * 512 + gx] = blv_s[c * 5 + t];

  stage_frame(0, ivr0);
  stage_frame(1, ivr1);
  __syncthreads();

  f32x4 acc2[4];
#pragma unroll
  for (int u = 0; u < 4; ++u) acc2[u] = (f32x4){0.f, 0.f, 0.f, 0.f};

#pragma unroll
  for (int tf = 0; tf < 5; ++tf) {
    // prefetch gi for frame tf+2 BEFORE conv1: conv1 phase covers the latency
    float ivr[5];
    if (tf < 3) issue_loads(tf + 2, ivr);

    // conv2 A fragments for this frame
    union { uint4 u; f16x8 v; } aw[5];
#pragma unroll
    for (int s = 0; s < 5; ++s)
      aw[s].u = *(const uint4*)(w2Ag + ((tf * 5 + s) * 64 + lane) * 8);

    // per-tf conv1 slot bases
    int baseE[8];
#pragma unroll
    for (int e = 0; e < 8; ++e) {
      int f = tf + kdE[e] - 1;
      int sl = (f < 0 || f > 4 || kdE[e] == 99) ? 3 : (f % 3);
      baseE[e] = sbase[e] + sl * 1320;
    }

    // ---- conv1 via MFMA ----
#pragma unroll
    for (int i = 0; i < 6; ++i) {
      if (i == 5 && wv != 0) continue;   // only wave 0 owns tile 20
      const int q = qT[i];
      uint u0[8], u1[8];
#pragma unroll
      for (int e = 0; e < 8; ++e) {
        const uint* pu = (const uint*)(xsh + (baseE[e] + q));
        u0[e] = pu[0]; u1[e] = pu[1];
      }
      f32x4 acc = bias4;
#pragma unroll
      for (int m = 0; m < 4; ++m) {
        union { uint4 u; bf16x8 v; } bfr;
        bfr.u = make_uint4(u0[2 * m], u1[2 * m], u0[2 * m + 1], u1[2 * m + 1]);
        acc = __builtin_amdgcn_mfma_f32_16x16x32_bf16(a4[m].v, bfr.v, acc, 0, 0, 0);
      }
      const bool inimg = (tmask >> (i + 8)) & 1u;
      float r0 = inimg ? leakyf(acc[0]) : 0.f;
      float r1 = inimg ? leakyf(acc[1]) : 0.f;
      float r2 = inimg ? leakyf(acc[2]) : 0.f;
      float r3 = inimg ? leakyf(acc[3]) : 0.f;
      uint p0 = cvt_pk_u32(r0, r1);
      uint p1 = cvt_pk_u32(r2, r3);
      if ((tmask >> i) & 1u)
        *(uint2*)(h2sh + hOffT[i]) = make_uint2(p0, p1);
    }
    __syncthreads();

    // ---- conv2(tf) MFMA, then x-write(tf+2) from prefetched regs ----
#pragma unroll
    for (int u = 0; u < 4; ++u) {
      const int tt = wv + u * 4;
      const ushort* hb = h2sh + tt * HROW;
#pragma unroll
      for (int s = 0; s < 5; ++s) {
        uint2 lo = *(const uint2*)(hb + bOff[s]);
        uint2 hi = *(const uint2*)(hb + bOff[s] + 4);
        union { uint4 u4; f16x8 v; } bfr;
        bfr.u4 = make_uint4(lo.x, lo.y, hi.x, hi.y);
        acc2[u] = __builtin_amdgcn_mfma_f32_16x16x32_f16(aw[s].v, bfr.v, acc2[u], 0, 0, 0);
      }
    }

    if (tf < 3) stage_frame(tf + 2, ivr);
    __syncthreads();
  }

  // ---- redistribute D[t][pos] through LDS (reuse xsh) and store t-output ----
  float* sredf = (float*)xsh;
#pragma unroll
  for (int u = 0; u < 4; ++u) {
    const int tt = wv + u * 4;
    if (kb == 0) {
#pragma unroll
      for (int r = 0; r < 4; ++r)
        sredf[r * 256 + tt * 16 + ln] = acc2[u][r];      // rows 0..3 = t 0..3
    } else if (kb == 1) {
      sredf[4 * 256 + tt * 16 + ln] = acc2[u][0];        // row 4 = t 4
    }
  }
  __syncthreads();

  const float bt2 = b_t2[0];
#pragma unroll
  for (int t = 0; t < 5; ++t) {
    float tv = 1.f / (1.f + __expf(-(sredf[t * 256 + tid] + bt2))) + t_bias[t];
    out[15728640 + ((b * 5 + t) * 512 + gy) * 512 + gx] = tv;
  }
}

extern "C" void kernel_launch(void* const* d_in, const int* in_sizes, int n_in,
                              void* d_out, int out_size, void* d_ws, size_t ws_size,
                              hipStream_t stream) {
  const float* gi = (const float*)d_in[0];
  const float* gj = (const float*)d_in[1];
  const float* w_bl1 = (const float*)d_in[2];
  const float* b_bl1 = (const float*)d_in[3];
  const float* w_bl2 = (const float*)d_in[4];
  const float* b_bl2 = (const float*)d_in[5];
  const float* w_t1 = (const float*)d_in[6];
  const float* b_t1 = (const float*)d_in[7];
  const float* w_t2 = (const float*)d_in[8];
  const float* b_t2 = (const float*)d_in[9];
  const float* w1 = (const float*)d_in[10];
  const float* w2 = (const float*)d_in[11];
  const float* t_bias = (const float*)d_in[12];
  float* out = (float*)d_out;
  char* ws = (char*)d_ws;

  uint* hist = (uint*)(ws + WS_HIST);
  double* sums = (double*)(ws + WS_DBL);
  float* blv = (float*)(ws + WS_BLV);
  ushort* wA = (ushort*)(ws + WS_WA);
  ushort* w2A = (ushort*)(ws + WS_W2A);

  hipMemsetAsync(ws, 0, WS_ZERO_BYTES, stream);

  setup_kernel<<<1, 256, 0, stream>>>(w_t1, w_t2, wA, w2A);
  stats_kernel<<<dim3(32, 72), 256, 0, stream>>>(gi, gj, sums, hist);
  finalize_kernel<<<1, 256, 0, stream>>>(hist, sums, w_bl1, b_bl1, w_bl2, b_bl2, w1, blv);
  fused_kernel<<<dim3(32, 32, 4), 256, 0, stream>>>(gi, gj, wA, b_t1, w2A, b_t2, w2, t_bias, blv, out);
}

// Round 13
// 151.477 us; speedup vs baseline: 1.3011x; 1.1311x over previous
//
#include <hip/hip_runtime.h>

typedef unsigned int uint;
typedef unsigned short ushort;
typedef short bf16x8 __attribute__((ext_vector_type(8)));
typedef _Float16 f16x8 __attribute__((ext_vector_type(8)));
typedef float f32x4 __attribute__((ext_vector_type(4)));

#define NEG_SLOPE 0.2f

// ---------------- workspace layout (bytes) ----------------
#define WS_HIST 0                       // 4*4096*4 = 65536
#define WS_DBL  65536                   // 88 doubles
#define WS_BLV  (WS_DBL + 704)         // 60 floats
#define WS_WA   (WS_BLV + 256)        // 16x128 bf16 = 4096 B
#define WS_W2A  (WS_WA + 4096)        // 5tf x 5step x 64lane x 8 f16 = 25600 B
#define WS_ZERO_BYTES (WS_DBL + 704)

// h2 LDS geometry: [18 rows][18 cols][28 ch-stride] (56B position stride = 14 banks,
// ln*7 mod 32 is a permutation -> conflict-free conv2 reads / conv1 writes)
#define HCH 28
#define HROW 504      // 18*28

__device__ __forceinline__ float leakyf(float x) { return fmaxf(x, NEG_SLOPE * x); }

__device__ __forceinline__ ushort f2bf(float f) {
  uint u = __float_as_uint(f);
  uint r = u + 0x7FFFu + ((u >> 16) & 1u);
  return (ushort)(r >> 16);
}
// pack 2 f32 -> 2 f16 in one dword (v_cvt_pkrtz_f16_f32)
__device__ __forceinline__ uint cvt_pk_u32(float a, float b) {
  union { __fp16 __attribute__((ext_vector_type(2))) h; uint u; } c;
  c.h = __builtin_amdgcn_cvt_pkrtz(a, b);
  return c.u;
}

// ---------------- fused stats: i-plane sums + center G/B stats + median hist + j sums ----------------
__global__ __launch_bounds__(256) void stats_kernel(const float* __restrict__ gi,
                                                    const float* __restrict__ gj,
                                                    double* __restrict__ sums,
                                                    uint* __restrict__ hist) {
  __shared__ double red[256];
  __shared__ uint lh[4096];
  const int plane = blockIdx.y;          // 0..59 = i planes, 60..71 = j planes
  const int chunk = blockIdx.x;          // 0..31
  const int tid = threadIdx.x;

  if (plane >= 60) {
    const int jp = plane - 60;
    const float4* base = (const float4*)(gj + (size_t)jp * 262144);
    double dsum = 0.0;
    for (int k = 0; k < 8; ++k) {
      float4 v = base[chunk * 2048 + k * 256 + tid];
      dsum += (double)v.x + (double)v.y + (double)v.z + (double)v.w;
    }
    red[tid] = dsum; __syncthreads();
    for (int off = 128; off > 0; off >>= 1) { if (tid < off) red[tid] += red[tid + off]; __syncthreads(); }
    if (tid == 0) atomicAdd(&sums[60 + jp], red[0]);
    return;
  }

  const int b = plane / 15;
  const int rem = plane % 15;
  const int c = rem / 5;
  const int t = rem % 5;
  const float4* base = (const float4*)(gi + (size_t)plane * 262144);
  const bool dostat = (c >= 1 && t == 2);
  const bool domed = (c == 0 && t == 2);
  if (domed) {
    for (int i = tid; i < 4096; i += 256) lh[i] = 0;
    __syncthreads();
  }
  double dsum = 0.0, dsx = 0.0, dsx2 = 0.0;
  for (int k = 0; k < 8; ++k) {
    float4 v = base[chunk * 2048 + k * 256 + tid];
    dsum += (double)v.x + (double)v.y + (double)v.z + (double)v.w;
    if (dostat || domed) {
      float arr[4] = {v.x, v.y, v.z, v.w};
#pragma unroll
      for (int q = 0; q < 4; ++q) {
        float x = fminf(fmaxf(arr[q], 0.f), 1.f) * 255.f;
        if (domed) {
          int bin = (int)(x * (4096.0f / 255.0f));
          if (bin > 4095) bin = 4095;
          atomicAdd(&lh[bin], 1u);
        } else {
          dsx += (double)x;
          dsx2 += (double)x * (double)x;
        }
      }
    }
  }
  red[tid] = dsum; __syncthreads();
  for (int off = 128; off > 0; off >>= 1) { if (tid < off) red[tid] += red[tid + off]; __syncthreads(); }
  if (tid == 0) atomicAdd(&sums[plane], red[0]);
  __syncthreads();
  if (dostat) {
    red[tid] = dsx; __syncthreads();
    for (int off = 128; off > 0; off >>= 1) { if (tid < off) red[tid] += red[tid + off]; __syncthreads(); }
    if (tid == 0) atomicAdd(&sums[72 + b * 2 + (c - 1)], red[0]);
    __syncthreads();
    red[tid] = dsx2; __syncthreads();
    for (int off = 128; off > 0; off >>= 1) { if (tid < off) red[tid] += red[tid + off]; __syncthreads(); }
    if (tid == 0) atomicAdd(&sums[80 + b * 2 + (c - 1)], red[0]);
  }
  if (domed) {
    for (int i = tid; i < 4096; i += 256) { uint v = lh[i]; if (v) atomicAdd(&hist[b * 4096 + i], v); }
  }
}

// ---------------- weight prep: bf16 conv1 A (16x128) + f16 conv2 A-table ----------------
__global__ void setup_kernel(const float* __restrict__ w_t1, const float* __restrict__ w_t2,
                             ushort* __restrict__ wA, ushort* __restrict__ w2A) {
  const int tid = threadIdx.x;
  for (int idx = tid; idx < 2048; idx += 256) {
    int o = idx >> 7, k = idx & 127, g = k >> 2, kw = k & 3;
    float v = 0.f;
    if (g < 27 && kw < 3) {
      int ci = g / 9, kd = (g % 9) / 3, kh = g % 3;
      v = w_t1[o * 81 + ci * 27 + kd * 9 + kh * 3 + kw];
    }
    wA[idx] = f2bf(v);
  }
  for (int idx = tid; idx < 12800; idx += 256) {
    int j = idx & 7;
    int lane = (idx >> 3) & 63;
    int rest = idx >> 9;            // 0..24
    int step = rest % 5;
    int tf = rest / 5;
    int ln = lane & 15, kb = lane >> 4;
    int k = kb * 8 + j;
    int tap = step * 2 + (k >> 4);
    int ch = k & 15;
    float v = 0.f;
    if (ln < 5 && tap < 9) {
      int kd = tf + 1 - ln;
      if (kd >= 0 && kd <= 2) v = w_t2[ch * 27 + kd * 9 + tap];
    }
    union { ushort s; _Float16 h; } cv; cv.h = (_Float16)v;
    w2A[idx] = cv.s;
  }
}

// ---------------- finalize: median scan + stats -> MLP -> blv ----------------
__global__ __launch_bounds__(256) void finalize_kernel(const uint* __restrict__ hist,
                                const double* __restrict__ sums,
                                const float* __restrict__ w_bl1, const float* __restrict__ b_bl1,
                                const float* __restrict__ w_bl2, const float* __restrict__ b_bl2,
                                const float* __restrict__ w1, float* __restrict__ blv) {
  __shared__ uint s[256];
  __shared__ float fv[2];
  __shared__ float rmed_s[4];
  const int tid = threadIdx.x;
  for (int b = 0; b < 4; ++b) {
    const uint* h = hist + b * 4096;
    uint loc[16]; uint part = 0;
#pragma unroll
    for (int q = 0; q < 16; ++q) { loc[q] = h[tid * 16 + q]; part += loc[q]; }
    s[tid] = part; __syncthreads();
    for (int off = 1; off < 256; off <<= 1) {
      uint v = (tid >= off) ? s[tid - off] : 0u;
      __syncthreads(); s[tid] += v; __syncthreads();
    }
    uint pref = s[tid] - part;
#pragma unroll
    for (int m = 0; m < 2; ++m) {
      uint k = 131071u + (uint)m;
      if (k >= pref && k < pref + part) {
        uint cum = pref;
        for (int q = 0; q < 16; ++q) {
          if (k < cum + loc[q]) { fv[m] = ((float)(tid * 16 + q) + 0.5f) * (255.f / 4096.f); break; }
          cum += loc[q];
        }
      }
    }
    __syncthreads();
    if (tid == 0) rmed_s[b] = 0.5f * (fv[0] + fv[1]);
    __syncthreads();
  }
  if (tid < 20) {
    const int b = tid / 5, t = tid % 5;
    const double inv = 1.0 / 262144.0;
    float bl2[3];
    bl2[0] = 140.f / (1.f + 14.4f * expf(-0.034f * rmed_s[b]));
    for (int c = 1; c < 3; ++c) {
      double m = sums[72 + b * 2 + (c - 1)] * inv;
      double ex2 = sums[80 + b * 2 + (c - 1)] * inv;
      double var = ex2 - m * m;
      if (var < 0.0) var = 0.0;
      bl2[c] = (float)(1.13 * m + 1.11 * sqrt(var) - 25.6);
    }
#pragma unroll
    for (int c = 0; c < 3; ++c)
      bl2[c] = fminf(fmaxf(bl2[c], 5.f), 250.f) * (1.f / 255.f);
    float diff[3];
    for (int c = 0; c < 3; ++c)
      diff[c] = (float)((sums[(b * 3 + c) * 5 + t] - sums[60 + b * 3 + c]) * inv);
    float h1[16];
    for (int o = 0; o < 16; ++o) {
      float sv = b_bl1[o];
      for (int c = 0; c < 3; ++c) sv += w_bl1[o * 3 + c] * diff[c];
      h1[o] = leakyf(sv);
    }
    const float w1v = w1[0];
    for (int c = 0; c < 3; ++c) {
      float sv = b_bl2[c];
      for (int o = 0; o < 16; ++o) sv += w_bl2[c * 16 + o] * h1[o];
      float sg = 1.f / (1.f + expf(-sv));
      blv[(b * 3 + c) * 5 + t] = bl2[c] + w1v * sg;
    }
  }
}

// ---------------- fused: x -> conv1 (MFMA bf16) -> leaky -> conv2 (MFMA f16) -> sigmoid ----------------
// R12 schedule; register diet: baseTab in LDS, qT|pe packed, civ nibble-packed, per-m conv1 loads.
__global__ __launch_bounds__(256, 3) void fused_kernel(
    const float* __restrict__ gi, const float* __restrict__ gj,
    const ushort* __restrict__ wAg, const float* __restrict__ b_t1,
    const ushort* __restrict__ w2Ag, const float* __restrict__ b_t2,
    const float* __restrict__ w2p, const float* __restrict__ t_bias,
    const float* __restrict__ blv, float* __restrict__ out) {
  __shared__ __align__(16) ushort xsh[10560];      // 2 parity copies x 4 slots x [3][20][22] bf16
  __shared__ __align__(16) ushort h2sh[324 * HCH]; // h2 f16 [18y][18x][28ch-stride]
  __shared__ __align__(16) int baseTab[160];       // [tf][kb][e] conv1 slot bases
  __shared__ float blv_s[15];

  const int b = blockIdx.z;
  // XCD-aware swizzle: lin%8 = XCD; each XCD gets a contiguous 4-row tile band (L2-resident halos)
  const int lin = blockIdx.y * 32 + blockIdx.x;
  const int swz = (lin & 7) * 128 + (lin >> 3);
  const int tY = swz >> 5, tX = swz & 31;
  const int tid = threadIdx.x;
  const int wv = tid >> 6;
  const int lane = tid & 63;
  const int ln = lane & 15;
  const int kb = lane >> 4;
  const int ty = tid >> 4, tx = tid & 15;
  const int gy = tY * 16 + ty, gx = tX * 16 + tx;
  const int ybase = tY * 16 - 2, xbase = tX * 16 - 2;

  if (tid < 15) blv_s[tid] = blv[b * 15 + tid];
  for (int i = tid; i < 5280; i += 256) ((uint*)xsh)[i] = 0u;
  // baseTab[tf][kb][e]: conv1 LDS base for k-group e of lane-group kb at frame tf
  if (tid < 160) {
    int tf_ = tid >> 5, kb_ = (tid >> 3) & 3, e = tid & 7;
    int g = (e >> 1) * 8 + kb_ * 2 + (e & 1);
    int sl = 3, sb = 0;
    if (g < 27) {
      int ci = g / 9, r9 = g % 9, kd = r9 / 3, kh = r9 % 3;
      sb = ci * 440 + kh * 22;
      int f = tf_ + kd - 1;
      if (f >= 0 && f <= 4) sl = f % 3;
    }
    baseTab[tid] = sb + sl * 1320;
  }

  // conv1 A fragments + bias
  union { uint4 u; bf16x8 v; } a4[4];
#pragma unroll
  for (int m = 0; m < 4; ++m)
    a4[m].u = *(const uint4*)(wAg + ln * 128 + m * 32 + kb * 8);
  f32x4 bias4;
#pragma unroll
  for (int r = 0; r < 4; ++r) bias4[r] = b_t1[kb * 4 + r];

  // conv1 per-tile statics (tile = wv + i*4): pT = q | (pe<<13)
  int pT[6];
  uint tmask = 0;   // bit i: pos<324 (store valid); bit i+8: inimg
#pragma unroll
  for (int i = 0; i < 6; ++i) {
    int tile = wv + i * 4;
    int pos = tile * 16 + ln;
    int pe = pos < 324 ? pos : 323;
    int y0 = pe / 18, x0 = pe - y0 * 18;
    int p = x0 & 1;
    pT[i] = (y0 * 22 + x0 - p + p * 5280) | (pe << 13);
    int gyh = tY * 16 - 1 + y0, gxh = tX * 16 - 1 + x0;
    if (pos < 324) tmask |= 1u << i;
    if (gyh >= 0 && gyh < 512 && gxh >= 0 && gxh < 512) tmask |= 1u << (i + 8);
  }

  // conv2 per-lane B offsets (elem units)
  int bOff[5];
#pragma unroll
  for (int s = 0; s < 5; ++s) {
    int tap = s * 2 + (kb >> 1); if (tap > 8) tap = 8;
    int kh = tap / 3, kw = tap - kh * 3;
    bOff[s] = kh * HROW + kw * HCH + (kb & 1) * 8 + ln * HCH;
  }

  // staging precompute (k = 0..4, idx = tid + k*256 over [3][20][20])
  int qi5[5], eb5[5];
  uint civpack = 0;
  float jv5[5];
  uint vmask = 0;
#pragma unroll
  for (int k = 0; k < 5; ++k) {
    int idx = tid + k * 256;
    int idc = idx < 1200 ? idx : 0;
    int ci = idc / 400, rem = idc - ci * 400;
    int ys = rem / 20, xx = rem - ys * 20;
    int gyy = ybase + ys, gxx = xbase + xx;
    bool inb = (idx < 1200) && gyy >= 0 && gyy < 512 && gxx >= 0 && gxx < 512;
    int cy = gyy < 0 ? 0 : (gyy > 511 ? 511 : gyy);
    int cx = gxx < 0 ? 0 : (gxx > 511 ? 511 : gxx);
    int spc = cy * 512 + cx;
    qi5[k] = (b * 3 + ci) * 1310720 + spc;
    jv5[k] = gj[(b * 3 + ci) * 262144 + spc];
    eb5[k] = ci * 440 + ys * 22 + xx;
    civpack |= (uint)(ci * 5) << (k * 4);
    if (inb) vmask |= 1u << k;
    if (xx > 0) vmask |= 1u << (k + 8);
  }

  const float w2v = w2p[0];

  auto issue_loads = [&](int f, float* ivr) {
    const int fo = f * 262144;
    ivr[0] = gi[qi5[0] + fo];
    ivr[1] = gi[qi5[1] + fo];
    ivr[2] = gi[qi5[2] + fo];
    ivr[3] = gi[qi5[3] + fo];
    ivr[4] = (tid < 176) ? gi[qi5[4] + fo] : 0.f;
  };
  auto stage_frame = [&](int f, const float* ivr) {
    const int slot = f % 3;
    const int sb2 = slot * 1320;
#pragma unroll
    for (int k = 0; k < 5; ++k) {
      if (k == 4 && tid >= 176) break;
      float iv = ivr[k];
      float bv = blv_s[((civpack >> (k * 4)) & 15u) + f];
      float num = iv - bv;
      float den = jv5[k] - bv + 1e-8f;
      float xv = ((vmask >> k) & 1u) ? fmaf(w2v, num * __builtin_amdgcn_rcpf(den), iv) : 0.f;
      ushort hx = f2bf(xv);
      int ebb = sb2 + eb5[k];
      xsh[ebb] = hx;
      if ((vmask >> (k + 8)) & 1u) xsh[ebb + 5279] = hx;
    }
  };

  // ---- prologue: issue loads for frames 0,1; barrier; bl writes; stage 0,1 ----
  float ivr0[5], ivr1[5];
  issue_loads(0, ivr0);
  issue_loads(1, ivr1);

  __syncthreads();   // zero-init + blv_s + baseTab visible to ALL waves

#pragma unroll
  for (int c = 0; c < 3; ++c)
#pragma unroll
    for (int t = 0; t < 5; ++t)
      out[(((b * 3 + c) * 5 + t) * 512 + gy) * 512 + gx] = blv_s[c * 5 + t];

  stage_frame(0, ivr0);
  stage_frame(1, ivr1);
  __syncthreads();

  f32x4 acc2[4];
#pragma unroll
  for (int u = 0; u < 4; ++u) acc2[u] = (f32x4){0.f, 0.f, 0.f, 0.f};

#pragma unroll
  for (int tf = 0; tf < 5; ++tf) {
    // prefetch gi for frame tf+2 BEFORE conv1: conv1 phase covers the latency
    float ivr[5];
    if (tf < 3) issue_loads(tf + 2, ivr);

    // conv2 A fragments for this frame
    union { uint4 u; f16x8 v; } aw[5];
#pragma unroll
    for (int s = 0; s < 5; ++s)
      aw[s].u = *(const uint4*)(w2Ag + ((tf * 5 + s) * 64 + lane) * 8);

    // per-tf conv1 slot bases from LDS table (2 x b128)
    int4 bE0 = *(const int4*)&baseTab[tf * 32 + kb * 8];
    int4 bE1 = *(const int4*)&baseTab[tf * 32 + kb * 8 + 4];

    // ---- conv1 via MFMA ----
#pragma unroll
    for (int i = 0; i < 6; ++i) {
      if (i == 5 && wv != 0) continue;   // only wave 0 owns tile 20
      const int pT_ = pT[i];
      const int q = pT_ & 8191;
      f32x4 acc = bias4;
#pragma unroll
      for (int m = 0; m < 4; ++m) {
        int be0 = (m == 0) ? bE0.x : (m == 1) ? bE0.z : (m == 2) ? bE1.x : bE1.z;
        int be1 = (m == 0) ? bE0.y : (m == 1) ? bE0.w : (m == 2) ? bE1.y : bE1.w;
        const uint* p0 = (const uint*)(xsh + (be0 + q));
        const uint* p1 = (const uint*)(xsh + (be1 + q));
        union { uint4 u; bf16x8 v; } bfr;
        bfr.u = make_uint4(p0[0], p0[1], p1[0], p1[1]);
        acc = __builtin_amdgcn_mfma_f32_16x16x32_bf16(a4[m].v, bfr.v, acc, 0, 0, 0);
      }
      const bool inimg = (tmask >> (i + 8)) & 1u;
      float r0 = inimg ? leakyf(acc[0]) : 0.f;
      float r1 = inimg ? leakyf(acc[1]) : 0.f;
      float r2 = inimg ? leakyf(acc[2]) : 0.f;
      float r3 = inimg ? leakyf(acc[3]) : 0.f;
      uint p0 = cvt_pk_u32(r0, r1);
      uint p1 = cvt_pk_u32(r2, r3);
      if ((tmask >> i) & 1u)
        *(uint2*)(h2sh + ((pT_ >> 13) * HCH + kb * 4)) = make_uint2(p0, p1);
    }
    __syncthreads();

    // ---- conv2(tf) MFMA, then x-write(tf+2) from prefetched regs ----
#pragma unroll
    for (int u = 0; u < 4; ++u) {
      const int tt = wv + u * 4;
      const ushort* hb = h2sh + tt * HROW;
#pragma unroll
      for (int s = 0; s < 5; ++s) {
        uint2 lo = *(const uint2*)(hb + bOff[s]);
        uint2 hi = *(const uint2*)(hb + bOff[s] + 4);
        union { uint4 u4; f16x8 v; } bfr;
        bfr.u4 = make_uint4(lo.x, lo.y, hi.x, hi.y);
        acc2[u] = __builtin_amdgcn_mfma_f32_16x16x32_f16(aw[s].v, bfr.v, acc2[u], 0, 0, 0);
      }
    }

    if (tf < 3) stage_frame(tf + 2, ivr);
    __syncthreads();
  }

  // ---- redistribute D[t][pos] through LDS (reuse xsh) and store t-output ----
  float* sredf = (float*)xsh;
#pragma unroll
  for (int u = 0; u < 4; ++u) {
    const int tt = wv + u * 4;
    if (kb == 0) {
#pragma unroll
      for (int r = 0; r < 4; ++r)
        sredf[r * 256 + tt * 16 + ln] = acc2[u][r];      // rows 0..3 = t 0..3
    } else if (kb == 1) {
      sredf[4 * 256 + tt * 16 + ln] = acc2[u][0];        // row 4 = t 4
    }
  }
  __syncthreads();

  const float bt2 = b_t2[0];
#pragma unroll
  for (int t = 0; t < 5; ++t) {
    float tv = 1.f / (1.f + __expf(-(sredf[t * 256 + tid] + bt2))) + t_bias[t];
    out[15728640 + ((b * 5 + t) * 512 + gy) * 512 + gx] = tv;
  }
}

extern "C" void kernel_launch(void* const* d_in, const int* in_sizes, int n_in,
                              void* d_out, int out_size, void* d_ws, size_t ws_size,
                              hipStream_t stream) {
  const float* gi = (const float*)d_in[0];
  const float* gj = (const float*)d_in[1];
  const float* w_bl1 = (const float*)d_in[2];
  const float* b_bl1 = (const float*)d_in[3];
  const float* w_bl2 = (const float*)d_in[4];
  const float* b_bl2 = (const float*)d_in[5];
  const float* w_t1 = (const float*)d_in[6];
  const float* b_t1 = (const float*)d_in[7];
  const float* w_t2 = (const float*)d_in[8];
  const float* b_t2 = (const float*)d_in[9];
  const float* w1 = (const float*)d_in[10];
  const float* w2 = (const float*)d_in[11];
  const float* t_bias = (const float*)d_in[12];
  float* out = (float*)d_out;
  char* ws = (char*)d_ws;

  uint* hist = (uint*)(ws + WS_HIST);
  double* sums = (double*)(ws + WS_DBL);
  float* blv = (float*)(ws + WS_BLV);
  ushort* wA = (ushort*)(ws + WS_WA);
  ushort* w2A = (ushort*)(ws + WS_W2A);

  hipMemsetAsync(ws, 0, WS_ZERO_BYTES, stream);

  setup_kernel<<<1, 256, 0, stream>>>(w_t1, w_t2, wA, w2A);
  stats_kernel<<<dim3(32, 72), 256, 0, stream>>>(gi, gj, sums, hist);
  finalize_kernel<<<1, 256, 0, stream>>>(hist, sums, w_bl1, b_bl1, w_bl2, b_bl2, w1, blv);
  fused_kernel<<<dim3(32, 32, 4), 256, 0, stream>>>(gi, gj, wA, b_t1, w2A, b_t2, w2, t_bias, blv, out);
}